// Round 1
// baseline (159.831 us; speedup 1.0000x reference)
//
#include <hip/hip_runtime.h>
#include <math.h>

#define B_ 2
#define F_ 128
#define N_ 192
#define S_ 192
#define NS_ (N_ * S_)          // 36864
#define SLOPE 0.2f
#define LOG2E 1.4426950408889634f
#define NEG_INF (-__builtin_inff())

#if defined(__has_builtin)
#if __has_builtin(__builtin_amdgcn_exp2f)
#define EXP2(x) __builtin_amdgcn_exp2f(x)
#else
#define EXP2(x) exp2f(x)
#endif
#else
#define EXP2(x) exp2f(x)
#endif

// Workspace layout (float offsets)
#define OFF_WSRC 0             // [f*4+h] * LOG2E
#define OFF_WDST 512
#define OFF_CSRC 1024          // (c_src[h] + b_attn) * LOG2E
#define OFF_CDST 1028
#define OFF_SUMG 1040          // [h*64+d]
#define OFF_PART 1296          // [sq 4][b 2][f 128] xsum partials
// exp-pair arrays (float2 each). exp(lrelu(p+q)) == max(E1*F1, E2*F2):
#define OFF_PE   2320                     // float2 [bh][i][s] = (exp2(p), exp2(.2p)); masked -> (0,0)
#define OFF_QD   (OFF_PE + 8 * NS_ * 2)   // float2 [bh][s][j] = (exp2(q), exp2(.2q))
#define OFF_QT   (OFF_QD + 8 * NS_ * 2)   // float2 [bh][j][s]  (transposed copy)

// ---- kPre: blocks 0..1023 xsum partials; 1024: wsrc/wdst; 1025: csrc/cdst ----
__global__ __launch_bounds__(256) void kPre(const float* __restrict__ X,
                                            const float* __restrict__ W_lin,
                                            const float* __restrict__ b_lin,
                                            const float* __restrict__ W_attn,
                                            const float* __restrict__ b_attn,
                                            float* __restrict__ ws) {
    int blk = blockIdx.x, t = threadIdx.x;
    if (blk < 1024) {
        int sq = blk & 3, f = (blk >> 2) & 127, b = blk >> 9;
        const float4* p = (const float4*)(X + ((size_t)(b * F_ + f)) * NS_ + sq * 9216);
        float acc = 0.f;
#pragma unroll
        for (int k = 0; k < 9; k++) {
            float4 v = p[t + k * 256];
            acc += (v.x + v.y) + (v.z + v.w);
        }
        for (int o = 32; o; o >>= 1) acc += __shfl_down(acc, o, 64);
        __shared__ float red[4];
        if ((t & 63) == 0) red[t >> 6] = acc;
        __syncthreads();
        if (t == 0)
            ws[OFF_PART + sq * 256 + b * 128 + f] = (red[0] + red[1]) + (red[2] + red[3]);
    } else if (blk == 1024) {
        const float4* wa = (const float4*)W_attn;
        for (int c = t; c < 512; c += 256) {
            int f = c >> 2, h = c & 3;
            const float4* wl = (const float4*)(W_lin + f * 256 + h * 64);
            float as = 0.f, ad = 0.f;
#pragma unroll
            for (int q = 0; q < 16; q++) {
                float4 w = wl[q], a1 = wa[q], a2 = wa[16 + q];
                as += w.x * a1.x + w.y * a1.y + w.z * a1.z + w.w * a1.w;
                ad += w.x * a2.x + w.y * a2.y + w.z * a2.z + w.w * a2.w;
            }
            ws[OFF_WSRC + c] = as * LOG2E;
            ws[OFF_WDST + c] = ad * LOG2E;
        }
    } else {
        if (t < 4) {
            float c = 0.f;
            for (int d = 0; d < 64; d++) c += b_lin[t * 64 + d] * W_attn[d];
            ws[OFF_CSRC + t] = (c + b_attn[0]) * LOG2E;
        } else if (t < 8) {
            int h = t - 4;
            float c = 0.f;
            for (int d = 0; d < 64; d++) c += b_lin[h * 64 + d] * W_attn[64 + d];
            ws[OFF_CDST + h] = c * LOG2E;
        }
    }
}

// ---- kProj: blocks < 1152: (n, b, s-chunk of 64), f split 4-way across waves;
//      block 1152: sum_g. Epilogue now stores exp-pairs instead of raw logits. ----
__global__ __launch_bounds__(256) void kProj(const float* __restrict__ X,
                                             const int* __restrict__ A,
                                             const float* __restrict__ W_lin,
                                             const float* __restrict__ b_lin,
                                             float* __restrict__ ws) {
    __shared__ float4 wsl[128], wdl[128];
    __shared__ float red[4 * 64 * 9];     // [fq][lane][8 +1 pad]
    __shared__ float xs[128];
    __shared__ float wbuf[4096];
    int t = threadIdx.x, blk = blockIdx.x;
    if (blk < 1152) {
        int n = blk % 192, bsc = blk / 192;
        int b = bsc / 3, sc = bsc % 3;
        if (t < 128) {
            wsl[t] = ((const float4*)(ws + OFF_WSRC))[t];
            wdl[t] = ((const float4*)(ws + OFF_WDST))[t];
        }
        __syncthreads();
        int fq = t >> 6, lane = t & 63;
        int s = sc * 64 + lane;
        float aS[4] = {0, 0, 0, 0}, aD[4] = {0, 0, 0, 0};
        const float* xp = X + (size_t)(b * F_) * NS_ + n * S_ + s;
        int f0 = fq * 32;
#pragma unroll 8
        for (int fi = 0; fi < 32; fi++) {
            float x = xp[(size_t)(f0 + fi) * NS_];
            float4 w1 = wsl[f0 + fi], w2 = wdl[f0 + fi];
            aS[0] += x * w1.x; aS[1] += x * w1.y; aS[2] += x * w1.z; aS[3] += x * w1.w;
            aD[0] += x * w2.x; aD[1] += x * w2.y; aD[2] += x * w2.z; aD[3] += x * w2.w;
        }
        float* rp = red + t * 9;
#pragma unroll
        for (int h = 0; h < 4; h++) { rp[h] = aS[h]; rp[4 + h] = aD[h]; }
        __syncthreads();
        float2* PEp = (float2*)(ws + OFF_PE);
        float2* QDp = (float2*)(ws + OFF_QD);
        float2* QTp = (float2*)(ws + OFF_QT);
        // 512 cells: [s_loc 64][k 8]; k<4 -> src h=k, k>=4 -> dst h=k-4
#pragma unroll
        for (int c = t; c < 512; c += 256) {
            int s_loc = c >> 3, k = c & 7;
            float v = red[s_loc * 9 + k] + red[(64 + s_loc) * 9 + k] +
                      red[(128 + s_loc) * 9 + k] + red[(192 + s_loc) * 9 + k];
            int ss = sc * 64 + s_loc;
            if (k < 4) {
                int bh = b * 4 + k;
                bool masked = (A[ss * 192 + n] == 0);   // mask = A[s, i=n]
                float2 pr;
                if (masked) { pr.x = 0.f; pr.y = 0.f; }
                else {
                    float pt = v + ws[OFF_CSRC + k];
                    pr.x = EXP2(pt); pr.y = EXP2(0.2f * pt);
                }
                PEp[(size_t)bh * NS_ + n * 192 + ss] = pr;
            } else {
                int h = k - 4, bh = b * 4 + h;
                float dv = v + ws[OFF_CDST + h];
                float2 qr; qr.x = EXP2(dv); qr.y = EXP2(0.2f * dv);
                QDp[(size_t)bh * NS_ + ss * 192 + n] = qr;   // [s][j]
                QTp[(size_t)bh * NS_ + n * 192 + ss] = qr;   // [j][s]
            }
        }
    } else {
        // sum_g[c] = sum_f xsum[f] * W_lin[f][c] + 73728 * b_lin[c]
        if (t < 128) {
            float v = 0.f;
#pragma unroll
            for (int q = 0; q < 8; q++) v += ws[OFF_PART + q * 128 + t];
            xs[t] = v;
        }
        float acc = 0.f;
        for (int ch = 0; ch < 8; ch++) {
            const float4* s4 = (const float4*)(W_lin + ch * 4096);
            __syncthreads();
#pragma unroll
            for (int k = 0; k < 4; k++) ((float4*)wbuf)[t + k * 256] = s4[t + k * 256];
            __syncthreads();
#pragma unroll
            for (int fi = 0; fi < 16; fi++) acc += xs[ch * 16 + fi] * wbuf[fi * 256 + t];
        }
        ws[OFF_SUMG + t] = acc + 73728.f * b_lin[t];
    }
}

// ---- kAttn: 768 blocks (bh = blk&7 XCD swizzle, 2 i rows each), 384 thr.
//      Inner loops are pure {mul,mul,max,add/fma}: no exp, no lrelu. ----
__global__ __launch_bounds__(384) void kAttn(const float* __restrict__ ws,
                                             float* __restrict__ out) {
    int blk = blockIdx.x, t = threadIdx.x;
    int bh = blk & 7, iq = blk >> 3;        // iq 0..95
    int b = bh >> 2, h = bh & 3;
    __shared__ float4 pe4[192];             // [s] = (E1_row0, E2_row0, E1_row1, E2_row1)
    __shared__ float zpart[768];            // [sq][i_loc][j]
    __shared__ float zr_sh[384];            // [i_loc][j]
    __shared__ float sg_sh[64];
    const float2* PEp = (const float2*)(ws + OFF_PE) + (size_t)bh * NS_;
    const float2* QDp = (const float2*)(ws + OFF_QD) + (size_t)bh * NS_;
    const float2* QTp = (const float2*)(ws + OFF_QT) + (size_t)bh * NS_;
    if (t < 64) sg_sh[t] = ws[OFF_SUMG + h * 64 + t];
    if (t < 192) {
        float2 a = PEp[(iq * 2) * 192 + t];
        float2 c = PEp[(iq * 2 + 1) * 192 + t];
        pe4[t] = make_float4(a.x, a.y, c.x, c.y);
    }
    __syncthreads();

    // Pass A: Z[i][j] = sum_s max(E1*F1, E2*F2), s split in halves of 96
    {
        int sq = t / 192, j = t - sq * 192;
        float z0 = 0.f, z1 = 0.f;
#pragma unroll 8
        for (int s = sq * 96; s < sq * 96 + 96; s++) {
            float4 E = pe4[s];              // broadcast ds_read_b128
            float2 F = QDp[s * 192 + j];    // coalesced 8B
            z0 += fmaxf(E.x * F.x, E.y * F.y);
            z1 += fmaxf(E.z * F.x, E.w * F.y);
        }
        zpart[sq * 384 + j] = z0;
        zpart[sq * 384 + 192 + j] = z1;
    }
    __syncthreads();
    {
        float Z = zpart[t] + zpart[384 + t];
        zr_sh[t] = (Z != 0.f) ? (1.f / Z) : 0.f;   // all-masked row -> 0
    }
    __syncthreads();

    // Pass B: alpha-sum over j + fused broadcast epilogue
    {
        int i_loc = t / 192, s = t - i_loc * 192;
        float4 E4 = pe4[s];
        float Ex = i_loc ? E4.z : E4.x;
        float Ey = i_loc ? E4.w : E4.y;
        const float* zr = zr_sh + i_loc * 192;
        float acc = 0.f;
#pragma unroll 8
        for (int j = 0; j < 192; j++) {
            float2 G = QTp[j * 192 + s];    // coalesced 8B
            acc += fmaxf(Ex * G.x, Ey * G.y) * zr[j];
        }
        int i = iq * 2 + i_loc;
        float* op = out + (((size_t)(b * 256 + h * 64)) * 192 + i) * 192 + s;
#pragma unroll 8
        for (int d = 0; d < 64; d++)
            op[(size_t)d * NS_] = acc * sg_sh[d];
    }
}

extern "C" void kernel_launch(void* const* d_in, const int* in_sizes, int n_in,
                              void* d_out, int out_size, void* d_ws, size_t ws_size,
                              hipStream_t stream) {
    const float* X      = (const float*)d_in[0];
    const int*   A      = (const int*)d_in[1];
    const float* W_lin  = (const float*)d_in[2];
    const float* b_lin  = (const float*)d_in[3];
    const float* W_attn = (const float*)d_in[4];
    const float* b_attn = (const float*)d_in[5];
    float* out = (float*)d_out;
    float* ws  = (float*)d_ws;

    kPre<<<1026, 256, 0, stream>>>(X, W_lin, b_lin, W_attn, b_attn, ws);
    kProj<<<1153, 256, 0, stream>>>(X, A, W_lin, b_lin, ws);
    kAttn<<<768, 384, 0, stream>>>(ws, out);
}